// Round 2
// baseline (381.244 us; speedup 1.0000x reference)
//
#include <hip/hip_runtime.h>
#include <hip/hip_bf16.h>
#include <hip/hip_fp16.h>

typedef _Float16 half8 __attribute__((ext_vector_type(8)));
typedef float f32x4 __attribute__((ext_vector_type(4)));

#define GM 32768
#define GN 1024
#define GK 1024

// ---- GEMM geometry: 256x256 tile, BK=32, 8 waves (2x4), per-wave 128x64 output
#define BM 256
#define BN 256
#define BK 32
#define NT (GK / BK)           // 32 K-tiles
#define SLOT_BYTES 32768       // A: 256 rows x 64B = 16KB, B: 16KB
#define B_OFF 16384
#define A_HALF 8192
#define LDS_BYTES (3 * SLOT_BYTES)   // 96 KiB, 3-slot ring

#define AX_BLOCKS 2048
#define AW_BLOCKS 64
#define QX_BLOCKS 16384   // 16384*256*8 = 33,554,432 = GM*GK
#define QW_BLOCKS 512     // 512*256*8   =  1,048,576 = GN*GK

__device__ __forceinline__ float fp8_scale_from_amax(float amax) {
    // exact replication of reference: clip(448/(amax*2+1e-12), 1e-12, 1e12)
    float s = 448.0f / (amax * 2.0f + 1e-12f);
    return fminf(fmaxf(s, 1e-12f), 1e12f);
}

// ---------------- amax (fused x / w), 4-way unrolled ----------------
// x: 8,388,608 float4 / (2048*256) = 16 iters; w: 262,144 / (64*256) = 16 iters
__global__ __launch_bounds__(256) void amax_kernel(const float4* __restrict__ x,
                                                   const float4* __restrict__ w,
                                                   unsigned* __restrict__ amax_bits) {
    int b = blockIdx.x;
    const float4* src; unsigned* slot; int nb, bl;
    if (b < AX_BLOCKS) { src = x; slot = amax_bits + 0; nb = AX_BLOCKS; bl = b; }
    else               { src = w; slot = amax_bits + 1; nb = AW_BLOCKS; bl = b - AX_BLOCKS; }
    const size_t stride = (size_t)nb * 256;
    const float4* p = src + (size_t)bl * 256 + threadIdx.x;
    float m0 = 0.f, m1 = 0.f, m2 = 0.f, m3 = 0.f;
    #pragma unroll
    for (int j = 0; j < 4; ++j) {
        float4 a = p[0];
        float4 c = p[stride];
        float4 d = p[2 * stride];
        float4 e = p[3 * stride];
        p += 4 * stride;
        m0 = fmaxf(m0, fmaxf(fmaxf(fabsf(a.x), fabsf(a.y)), fmaxf(fabsf(a.z), fabsf(a.w))));
        m1 = fmaxf(m1, fmaxf(fmaxf(fabsf(c.x), fabsf(c.y)), fmaxf(fabsf(c.z), fabsf(c.w))));
        m2 = fmaxf(m2, fmaxf(fmaxf(fabsf(d.x), fabsf(d.y)), fmaxf(fabsf(d.z), fabsf(d.w))));
        m3 = fmaxf(m3, fmaxf(fmaxf(fabsf(e.x), fabsf(e.y)), fmaxf(fabsf(e.z), fabsf(e.w))));
    }
    float m = fmaxf(fmaxf(m0, m1), fmaxf(m2, m3));
    #pragma unroll
    for (int off = 32; off; off >>= 1) m = fmaxf(m, __shfl_xor(m, off));
    if ((threadIdx.x & 63) == 0) atomicMax(slot, __float_as_uint(m)); // m>=0 -> bits monotonic
}

// ---------------- quantize (fused x / w) ----------------
// Stores X8 = rint(clip(x*scale,-448,448)*8) as fp16 (integer <= 1792, exact).
__global__ __launch_bounds__(256) void quant_kernel(const float* __restrict__ x,
                                                    const float* __restrict__ w,
                                                    _Float16* __restrict__ X8,
                                                    _Float16* __restrict__ W8,
                                                    const unsigned* __restrict__ amax_bits) {
    int b = blockIdx.x;
    const float* src; _Float16* dst; int bl; int slot;
    if (b < QX_BLOCKS) { src = x; dst = X8; bl = b; slot = 0; }
    else               { src = w; dst = W8; bl = b - QX_BLOCKS; slot = 1; }
    float amax  = __uint_as_float(amax_bits[slot]);
    float scale = fp8_scale_from_amax(amax);
    size_t base = ((size_t)bl * 256 + threadIdx.x) * 8;
    float4 v0 = *(const float4*)(src + base);
    float4 v1 = *(const float4*)(src + base + 4);
    float vs[8] = {v0.x, v0.y, v0.z, v0.w, v1.x, v1.y, v1.z, v1.w};
    half8 h;
    #pragma unroll
    for (int j = 0; j < 8; ++j) {
        float s = vs[j] * scale;
        s = fminf(fmaxf(s, -448.0f), 448.0f);
        h[j] = (_Float16)rintf(s * 8.0f);   // rintf = round-half-even, matches jnp.round
    }
    *(half8*)(dst + base) = h;
}

// ---------------- GEMM: C = X8 * W8^T * r + bias ----------------
// 256^2 tile, BK=32, 512 threads (8 waves 2x4, each 128x64 out).
// 3-slot LDS ring: compute tile t while tile t+1 lands and tile t+2 is issued.
// Counted s_waitcnt vmcnt(4) per tile (never drains to 0 in the main loop).
// XOR bank swizzle: physical 16B-chunk = logical_chunk ^ ((row>>1)&3), applied
// by pre-swizzling the GLOBAL source address (global_load_lds writes linearly).
__global__ __launch_bounds__(512, 2) void gemm_kernel(const _Float16* __restrict__ A,  // [GM][GK]
                                                      const _Float16* __restrict__ B,  // [GN][GK]
                                                      const float* __restrict__ bias,
                                                      float* __restrict__ C,
                                                      const unsigned* __restrict__ amax_bits) {
    extern __shared__ char lds[];

    const int tid  = threadIdx.x;
    const int wid  = tid >> 6;
    const int lane = tid & 63;
    const int wr   = wid >> 2;      // 0..1  (row half of the block)
    const int wc   = wid & 3;       // 0..3  (col quarter)
    const int l16  = lane & 15;
    const int kq   = lane >> 4;     // 16B k-chunk index 0..3

    // XCD-aware swizzle: nwg = 512 = 8 XCDs x 64; bm-major within XCD chunk
    const int bid = blockIdx.x;
    const int swz = (bid & 7) * 64 + (bid >> 3);
    const int bm  = swz >> 2;       // 0..127
    const int bn  = swz & 3;        // 0..3
    const int row0 = bm * BM, col0 = bn * BN;

    // ---- staging setup (per-thread): 4 x global_load_lds(16B) per K-tile
    const int rho  = tid >> 2;                       // 0..127 (LDS row within half)
    const int kap  = tid & 3;                        // linear LDS chunk this thread fills
    const int coff = ((kap ^ ((rho >> 1) & 3)) << 3); // swizzled source element offset
    const _Float16* sA0 = A + (size_t)(row0 + rho) * GK + coff;
    const _Float16* sA1 = A + (size_t)(row0 + 128 + rho) * GK + coff;
    const _Float16* sB0 = B + (size_t)(col0 + rho) * GK + coff;
    const _Float16* sB1 = B + (size_t)(col0 + 128 + rho) * GK + coff;
    // wave-uniform LDS dests (HW adds lane*16)
    const int dA0 = wid * 1024;
    const int dA1 = A_HALF + wid * 1024;
    const int dB0 = B_OFF + wid * 1024;
    const int dB1 = B_OFF + A_HALF + wid * 1024;

    // ---- fragment read offsets (swizzle reduces to a per-lane constant:
    // (r>>1)&3 == (l16>>1)&3 because frag rows step by 16)
    const int rsw  = kq ^ ((l16 >> 1) & 3);
    const int offA = (wr * 128 + l16) * 64 + (rsw << 4);
    const int offB = B_OFF + (wc * 64 + l16) * 64 + (rsw << 4);

    f32x4 acc[8][4] = {};

#define STAGE(slotidx) do {                                                            \
    char* sb_ = lds + (slotidx) * SLOT_BYTES;                                          \
    __builtin_amdgcn_global_load_lds((const __attribute__((address_space(1))) void*)sA0, \
        (__attribute__((address_space(3))) void*)(sb_ + dA0), 16, 0, 0);               \
    __builtin_amdgcn_global_load_lds((const __attribute__((address_space(1))) void*)sA1, \
        (__attribute__((address_space(3))) void*)(sb_ + dA1), 16, 0, 0);               \
    __builtin_amdgcn_global_load_lds((const __attribute__((address_space(1))) void*)sB0, \
        (__attribute__((address_space(3))) void*)(sb_ + dB0), 16, 0, 0);               \
    __builtin_amdgcn_global_load_lds((const __attribute__((address_space(1))) void*)sB1, \
        (__attribute__((address_space(3))) void*)(sb_ + dB1), 16, 0, 0);               \
    sA0 += BK; sA1 += BK; sB0 += BK; sB1 += BK;                                        \
} while (0)

#define MM(f, av)                                                                  \
    acc[f][0] = __builtin_amdgcn_mfma_f32_16x16x32_f16(av, bf0, acc[f][0], 0, 0, 0); \
    acc[f][1] = __builtin_amdgcn_mfma_f32_16x16x32_f16(av, bf1, acc[f][1], 0, 0, 0); \
    acc[f][2] = __builtin_amdgcn_mfma_f32_16x16x32_f16(av, bf2, acc[f][2], 0, 0, 0); \
    acc[f][3] = __builtin_amdgcn_mfma_f32_16x16x32_f16(av, bf3, acc[f][3], 0, 0, 0);

#define COMPUTE(slotidx) do {                                  \
    const char* cb_ = lds + (slotidx) * SLOT_BYTES;            \
    half8 bf0 = *(const half8*)(cb_ + offB + 0 * 1024);        \
    half8 bf1 = *(const half8*)(cb_ + offB + 1 * 1024);        \
    half8 bf2 = *(const half8*)(cb_ + offB + 2 * 1024);        \
    half8 bf3 = *(const half8*)(cb_ + offB + 3 * 1024);        \
    half8 a0 = *(const half8*)(cb_ + offA + 0 * 1024);         \
    half8 a1 = *(const half8*)(cb_ + offA + 1 * 1024);         \
    half8 a2 = *(const half8*)(cb_ + offA + 2 * 1024);         \
    half8 a3 = *(const half8*)(cb_ + offA + 3 * 1024);         \
    __builtin_amdgcn_s_setprio(1);                             \
    MM(0, a0) MM(1, a1) MM(2, a2) MM(3, a3)                    \
    __builtin_amdgcn_s_setprio(0);                             \
    half8 a4 = *(const half8*)(cb_ + offA + 4 * 1024);         \
    half8 a5 = *(const half8*)(cb_ + offA + 5 * 1024);         \
    half8 a6 = *(const half8*)(cb_ + offA + 6 * 1024);         \
    half8 a7 = *(const half8*)(cb_ + offA + 7 * 1024);         \
    __builtin_amdgcn_s_setprio(1);                             \
    MM(4, a4) MM(5, a5) MM(6, a6) MM(7, a7)                    \
    __builtin_amdgcn_s_setprio(0);                             \
} while (0)

    STAGE(0);
    STAGE(1);
    for (int t = 0; t < NT; ++t) {
        // tile t's 4 loads are >= 8 loads old for every wave except at t=NT-1,
        // where nothing younger is outstanding -> drain.
        if (t < NT - 1) { asm volatile("s_waitcnt vmcnt(4)" ::: "memory"); }
        else            { asm volatile("s_waitcnt vmcnt(0)" ::: "memory"); }
        __builtin_amdgcn_s_barrier();
        asm volatile("" ::: "memory");   // pin LDS reads below the barrier
        if (t + 2 < NT) STAGE((t + 2) % 3);
        COMPUTE(t % 3);
    }

#undef STAGE
#undef COMPUTE
#undef MM

    // epilogue: out = acc / (64 * a_scale * w_scale) + bias
    float sa = fp8_scale_from_amax(__uint_as_float(amax_bits[0]));
    float sw = fp8_scale_from_amax(__uint_as_float(amax_bits[1]));
    float rs = 1.0f / (64.0f * sa * sw);

    const int orow = row0 + wr * 128 + kq * 4;
    const int ocol = col0 + wc * 64 + l16;
    float bvv[4];
    #pragma unroll
    for (int n = 0; n < 4; ++n) bvv[n] = bias[ocol + n * 16];
    #pragma unroll
    for (int f = 0; f < 8; ++f) {
        #pragma unroll
        for (int n = 0; n < 4; ++n) {
            const int cc = ocol + n * 16;
            #pragma unroll
            for (int i = 0; i < 4; ++i) {
                const int rr = orow + f * 16 + i;
                C[(size_t)rr * GN + cc] = acc[f][n][i] * rs + bvv[n];
            }
        }
    }
}

extern "C" void kernel_launch(void* const* d_in, const int* in_sizes, int n_in,
                              void* d_out, int out_size, void* d_ws, size_t ws_size,
                              hipStream_t stream) {
    const float* x    = (const float*)d_in[0];  // [32768][1024]
    const float* w    = (const float*)d_in[1];  // [1024][1024]
    const float* bias = (const float*)d_in[2];  // [1024]
    float* out        = (float*)d_out;          // [32768][1024]

    unsigned* amax_bits = (unsigned*)d_ws;
    _Float16* X8 = (_Float16*)((char*)d_ws + 256);
    _Float16* W8 = (_Float16*)((char*)d_ws + 256 + (size_t)GM * GK * 2);

    hipMemsetAsync(d_ws, 0, 8, stream);  // zero amax slots (ws is poisoned each call)

    amax_kernel<<<AX_BLOCKS + AW_BLOCKS, 256, 0, stream>>>(
        (const float4*)x, (const float4*)w, amax_bits);

    quant_kernel<<<QX_BLOCKS + QW_BLOCKS, 256, 0, stream>>>(x, w, X8, W8, amax_bits);

    (void)hipFuncSetAttribute((const void*)gemm_kernel,
                              hipFuncAttributeMaxDynamicSharedMemorySize, LDS_BYTES);
    gemm_kernel<<<(GM / BM) * (GN / BN), 512, LDS_BYTES, stream>>>(X8, W8, bias, out, amax_bits);
}

// Round 3
// 331.912 us; speedup vs baseline: 1.1486x; 1.1486x over previous
//
#include <hip/hip_runtime.h>
#include <hip/hip_bf16.h>
#include <hip/hip_fp16.h>

typedef _Float16 half8 __attribute__((ext_vector_type(8)));
typedef float f32x4 __attribute__((ext_vector_type(4)));

#define GM 32768
#define GN 1024
#define GK 1024

// ---- GEMM geometry: 256x256 tile, BK=32, 8 waves (2x4), per-wave 128x64 output
#define BM 256
#define BN 256
#define BK 32
#define NT (GK / BK)           // 32 K-tiles
#define SLOT_BYTES 32768       // A: 256 rows x 64B = 16KB, B: 16KB
#define B_OFF 16384
#define A_HALF 8192
#define LDS_BYTES (3 * SLOT_BYTES)   // 96 KiB, 3-slot ring

#define AX_BLOCKS 2048
#define AW_BLOCKS 64
#define QX_BLOCKS 16384   // 16384*256*8 = 33,554,432 = GM*GK
#define QW_BLOCKS 512     // 512*256*8   =  1,048,576 = GN*GK

__device__ __forceinline__ float fp8_scale_from_amax(float amax) {
    // exact replication of reference: clip(448/(amax*2+1e-12), 1e-12, 1e12)
    float s = 448.0f / (amax * 2.0f + 1e-12f);
    return fminf(fmaxf(s, 1e-12f), 1e12f);
}

// ---------------- amax partials (fused x / w) — NO atomics ----------------
// Per-block LDS reduce -> one plain store per block (atomicMax to a single
// address serialized at ~13ns/op: 8448 atomics was 110us. Partials avoid it.)
__global__ __launch_bounds__(256) void amax_kernel(const float4* __restrict__ x,
                                                   const float4* __restrict__ w,
                                                   float* __restrict__ px,
                                                   float* __restrict__ pw) {
    __shared__ float red[4];
    int b = blockIdx.x;
    const float4* src; float* dst; int nb, bl;
    if (b < AX_BLOCKS) { src = x; dst = px + b; nb = AX_BLOCKS; bl = b; }
    else               { src = w; dst = pw + (b - AX_BLOCKS); nb = AW_BLOCKS; bl = b - AX_BLOCKS; }
    const size_t stride = (size_t)nb * 256;
    const float4* p = src + (size_t)bl * 256 + threadIdx.x;
    float m0 = 0.f, m1 = 0.f, m2 = 0.f, m3 = 0.f;
    #pragma unroll
    for (int j = 0; j < 4; ++j) {
        float4 a = p[0];
        float4 c = p[stride];
        float4 d = p[2 * stride];
        float4 e = p[3 * stride];
        p += 4 * stride;
        m0 = fmaxf(m0, fmaxf(fmaxf(fabsf(a.x), fabsf(a.y)), fmaxf(fabsf(a.z), fabsf(a.w))));
        m1 = fmaxf(m1, fmaxf(fmaxf(fabsf(c.x), fabsf(c.y)), fmaxf(fabsf(c.z), fabsf(c.w))));
        m2 = fmaxf(m2, fmaxf(fmaxf(fabsf(d.x), fabsf(d.y)), fmaxf(fabsf(d.z), fabsf(d.w))));
        m3 = fmaxf(m3, fmaxf(fmaxf(fabsf(e.x), fabsf(e.y)), fmaxf(fabsf(e.z), fabsf(e.w))));
    }
    float m = fmaxf(fmaxf(m0, m1), fmaxf(m2, m3));
    #pragma unroll
    for (int off = 32; off; off >>= 1) m = fmaxf(m, __shfl_xor(m, off));
    const int lane = threadIdx.x & 63, wid = threadIdx.x >> 6;
    if (lane == 0) red[wid] = m;
    __syncthreads();
    if (threadIdx.x == 0)
        *dst = fmaxf(fmaxf(red[0], red[1]), fmaxf(red[2], red[3]));
}

// ---------------- final reduce: partials -> amax bits (1 block) ----------------
__global__ __launch_bounds__(256) void reduce_kernel(const float* __restrict__ px,
                                                     const float* __restrict__ pw,
                                                     unsigned* __restrict__ amax_bits) {
    __shared__ float red[8];
    const int tid = threadIdx.x, lane = tid & 63, wid = tid >> 6;
    float mx = 0.f;
    for (int i = tid; i < AX_BLOCKS; i += 256) mx = fmaxf(mx, px[i]);
    #pragma unroll
    for (int off = 32; off; off >>= 1) mx = fmaxf(mx, __shfl_xor(mx, off));
    if (lane == 0) red[wid] = mx;
    float mw = (tid < AW_BLOCKS) ? pw[tid] : 0.f;   // wave 0 covers all 64 w-partials
    #pragma unroll
    for (int off = 32; off; off >>= 1) mw = fmaxf(mw, __shfl_xor(mw, off));
    if (tid == 0) red[4] = mw;
    __syncthreads();
    if (tid == 0) {
        float a = fmaxf(fmaxf(red[0], red[1]), fmaxf(red[2], red[3]));
        amax_bits[0] = __float_as_uint(a);
        amax_bits[1] = __float_as_uint(red[4]);
    }
}

// ---------------- quantize (fused x / w) ----------------
// Stores X8 = rint(clip(x*scale,-448,448)*8) as fp16 (integer <= 1792, exact).
__global__ __launch_bounds__(256) void quant_kernel(const float* __restrict__ x,
                                                    const float* __restrict__ w,
                                                    _Float16* __restrict__ X8,
                                                    _Float16* __restrict__ W8,
                                                    const unsigned* __restrict__ amax_bits) {
    int b = blockIdx.x;
    const float* src; _Float16* dst; int bl; int slot;
    if (b < QX_BLOCKS) { src = x; dst = X8; bl = b; slot = 0; }
    else               { src = w; dst = W8; bl = b - QX_BLOCKS; slot = 1; }
    float amax  = __uint_as_float(amax_bits[slot]);
    float scale = fp8_scale_from_amax(amax);
    size_t base = ((size_t)bl * 256 + threadIdx.x) * 8;
    float4 v0 = *(const float4*)(src + base);
    float4 v1 = *(const float4*)(src + base + 4);
    float vs[8] = {v0.x, v0.y, v0.z, v0.w, v1.x, v1.y, v1.z, v1.w};
    half8 h;
    #pragma unroll
    for (int j = 0; j < 8; ++j) {
        float s = vs[j] * scale;
        s = fminf(fmaxf(s, -448.0f), 448.0f);
        h[j] = (_Float16)rintf(s * 8.0f);   // rintf = round-half-even, matches jnp.round
    }
    *(half8*)(dst + base) = h;
}

// ---------------- GEMM: C = X8 * W8^T * r + bias ----------------
// 256^2 tile, BK=32, 512 threads (8 waves 2x4, each 128x64 out).
// 3-slot LDS ring: compute tile t while tile t+1 lands and tile t+2 is issued.
// Counted s_waitcnt vmcnt(4) per tile (never drains to 0 in the main loop).
// XOR bank swizzle: physical 16B-chunk = logical_chunk ^ ((row>>1)&3), applied
// by pre-swizzling the GLOBAL source address (global_load_lds writes linearly).
__global__ __launch_bounds__(512, 2) void gemm_kernel(const _Float16* __restrict__ A,  // [GM][GK]
                                                      const _Float16* __restrict__ B,  // [GN][GK]
                                                      const float* __restrict__ bias,
                                                      float* __restrict__ C,
                                                      const unsigned* __restrict__ amax_bits) {
    extern __shared__ char lds[];

    const int tid  = threadIdx.x;
    const int wid  = tid >> 6;
    const int lane = tid & 63;
    const int wr   = wid >> 2;      // 0..1  (row half of the block)
    const int wc   = wid & 3;       // 0..3  (col quarter)
    const int l16  = lane & 15;
    const int kq   = lane >> 4;     // 16B k-chunk index 0..3

    // XCD-aware swizzle: nwg = 512 = 8 XCDs x 64; bm-major within XCD chunk
    const int bid = blockIdx.x;
    const int swz = (bid & 7) * 64 + (bid >> 3);
    const int bm  = swz >> 2;       // 0..127
    const int bn  = swz & 3;        // 0..3
    const int row0 = bm * BM, col0 = bn * BN;

    // ---- staging setup (per-thread): 4 x global_load_lds(16B) per K-tile
    const int rho  = tid >> 2;                       // 0..127 (LDS row within half)
    const int kap  = tid & 3;                        // linear LDS chunk this thread fills
    const int coff = ((kap ^ ((rho >> 1) & 3)) << 3); // swizzled source element offset
    const _Float16* sA0 = A + (size_t)(row0 + rho) * GK + coff;
    const _Float16* sA1 = A + (size_t)(row0 + 128 + rho) * GK + coff;
    const _Float16* sB0 = B + (size_t)(col0 + rho) * GK + coff;
    const _Float16* sB1 = B + (size_t)(col0 + 128 + rho) * GK + coff;
    // wave-uniform LDS dests (HW adds lane*16)
    const int dA0 = wid * 1024;
    const int dA1 = A_HALF + wid * 1024;
    const int dB0 = B_OFF + wid * 1024;
    const int dB1 = B_OFF + A_HALF + wid * 1024;

    // ---- fragment read offsets (swizzle reduces to a per-lane constant:
    // (r>>1)&3 == (l16>>1)&3 because frag rows step by 16)
    const int rsw  = kq ^ ((l16 >> 1) & 3);
    const int offA = (wr * 128 + l16) * 64 + (rsw << 4);
    const int offB = B_OFF + (wc * 64 + l16) * 64 + (rsw << 4);

    f32x4 acc[8][4] = {};

#define STAGE(slotidx) do {                                                            \
    char* sb_ = lds + (slotidx) * SLOT_BYTES;                                          \
    __builtin_amdgcn_global_load_lds((const __attribute__((address_space(1))) void*)sA0, \
        (__attribute__((address_space(3))) void*)(sb_ + dA0), 16, 0, 0);               \
    __builtin_amdgcn_global_load_lds((const __attribute__((address_space(1))) void*)sA1, \
        (__attribute__((address_space(3))) void*)(sb_ + dA1), 16, 0, 0);               \
    __builtin_amdgcn_global_load_lds((const __attribute__((address_space(1))) void*)sB0, \
        (__attribute__((address_space(3))) void*)(sb_ + dB0), 16, 0, 0);               \
    __builtin_amdgcn_global_load_lds((const __attribute__((address_space(1))) void*)sB1, \
        (__attribute__((address_space(3))) void*)(sb_ + dB1), 16, 0, 0);               \
    sA0 += BK; sA1 += BK; sB0 += BK; sB1 += BK;                                        \
} while (0)

#define MM(f, av)                                                                  \
    acc[f][0] = __builtin_amdgcn_mfma_f32_16x16x32_f16(av, bf0, acc[f][0], 0, 0, 0); \
    acc[f][1] = __builtin_amdgcn_mfma_f32_16x16x32_f16(av, bf1, acc[f][1], 0, 0, 0); \
    acc[f][2] = __builtin_amdgcn_mfma_f32_16x16x32_f16(av, bf2, acc[f][2], 0, 0, 0); \
    acc[f][3] = __builtin_amdgcn_mfma_f32_16x16x32_f16(av, bf3, acc[f][3], 0, 0, 0);

#define COMPUTE(slotidx) do {                                  \
    const char* cb_ = lds + (slotidx) * SLOT_BYTES;            \
    half8 bf0 = *(const half8*)(cb_ + offB + 0 * 1024);        \
    half8 bf1 = *(const half8*)(cb_ + offB + 1 * 1024);        \
    half8 bf2 = *(const half8*)(cb_ + offB + 2 * 1024);        \
    half8 bf3 = *(const half8*)(cb_ + offB + 3 * 1024);        \
    half8 a0 = *(const half8*)(cb_ + offA + 0 * 1024);         \
    half8 a1 = *(const half8*)(cb_ + offA + 1 * 1024);         \
    half8 a2 = *(const half8*)(cb_ + offA + 2 * 1024);         \
    half8 a3 = *(const half8*)(cb_ + offA + 3 * 1024);         \
    __builtin_amdgcn_s_setprio(1);                             \
    MM(0, a0) MM(1, a1) MM(2, a2) MM(3, a3)                    \
    __builtin_amdgcn_s_setprio(0);                             \
    half8 a4 = *(const half8*)(cb_ + offA + 4 * 1024);         \
    half8 a5 = *(const half8*)(cb_ + offA + 5 * 1024);         \
    half8 a6 = *(const half8*)(cb_ + offA + 6 * 1024);         \
    half8 a7 = *(const half8*)(cb_ + offA + 7 * 1024);         \
    __builtin_amdgcn_s_setprio(1);                             \
    MM(4, a4) MM(5, a5) MM(6, a6) MM(7, a7)                    \
    __builtin_amdgcn_s_setprio(0);                             \
} while (0)

    STAGE(0);
    STAGE(1);
    for (int t = 0; t < NT; ++t) {
        // tile t's 4 loads are >= 8 loads old for every wave except at t=NT-1,
        // where nothing younger is outstanding -> drain.
        if (t < NT - 1) { asm volatile("s_waitcnt vmcnt(4)" ::: "memory"); }
        else            { asm volatile("s_waitcnt vmcnt(0)" ::: "memory"); }
        __builtin_amdgcn_s_barrier();
        asm volatile("" ::: "memory");   // pin LDS reads below the barrier
        if (t + 2 < NT) STAGE((t + 2) % 3);
        COMPUTE(t % 3);
    }

#undef STAGE
#undef COMPUTE
#undef MM

    // epilogue: out = acc / (64 * a_scale * w_scale) + bias
    float sa = fp8_scale_from_amax(__uint_as_float(amax_bits[0]));
    float sw = fp8_scale_from_amax(__uint_as_float(amax_bits[1]));
    float rs = 1.0f / (64.0f * sa * sw);

    const int orow = row0 + wr * 128 + kq * 4;
    const int ocol = col0 + wc * 64 + l16;
    float bvv[4];
    #pragma unroll
    for (int n = 0; n < 4; ++n) bvv[n] = bias[ocol + n * 16];
    #pragma unroll
    for (int f = 0; f < 8; ++f) {
        #pragma unroll
        for (int n = 0; n < 4; ++n) {
            const int cc = ocol + n * 16;
            #pragma unroll
            for (int i = 0; i < 4; ++i) {
                const int rr = orow + f * 16 + i;
                C[(size_t)rr * GN + cc] = acc[f][n][i] * rs + bvv[n];
            }
        }
    }
}

extern "C" void kernel_launch(void* const* d_in, const int* in_sizes, int n_in,
                              void* d_out, int out_size, void* d_ws, size_t ws_size,
                              hipStream_t stream) {
    const float* x    = (const float*)d_in[0];  // [32768][1024]
    const float* w    = (const float*)d_in[1];  // [1024][1024]
    const float* bias = (const float*)d_in[2];  // [1024]
    float* out        = (float*)d_out;          // [32768][1024]

    unsigned* amax_bits = (unsigned*)d_ws;                       // 2 u32
    float* px = (float*)((char*)d_ws + 4096);                    // 2048 partials
    float* pw = px + AX_BLOCKS;                                  // 64 partials
    _Float16* X8 = (_Float16*)((char*)d_ws + 65536);
    _Float16* W8 = (_Float16*)((char*)d_ws + 65536 + (size_t)GM * GK * 2);

    amax_kernel<<<AX_BLOCKS + AW_BLOCKS, 256, 0, stream>>>(
        (const float4*)x, (const float4*)w, px, pw);

    reduce_kernel<<<1, 256, 0, stream>>>(px, pw, amax_bits);

    quant_kernel<<<QX_BLOCKS + QW_BLOCKS, 256, 0, stream>>>(x, w, X8, W8, amax_bits);

    (void)hipFuncSetAttribute((const void*)gemm_kernel,
                              hipFuncAttributeMaxDynamicSharedMemorySize, LDS_BYTES);
    gemm_kernel<<<(GM / BM) * (GN / BN), 512, LDS_BYTES, stream>>>(X8, W8, bias, out, amax_bits);
}